// Round 19
// baseline (870.329 us; speedup 1.0000x reference)
//
#include <hip/hip_runtime.h>

#define N_NODESC 50000
#define N_PAD 50176          // 392 * 128
#define N_EDGESC 800000
#define N_GRAPHSC 128
#define EMBEDC 256
#define MTILES 392
#define SLAB ((long)N_PAD * 32)   // halves per 32-col slice slab
#define NRANGE 6272               // N_PAD/8: node range per scatter slice

typedef __attribute__((ext_vector_type(8))) _Float16 hf8;
typedef __attribute__((ext_vector_type(4))) float fx4;

__device__ __forceinline__ float h2f(unsigned short u) {
  _Float16 h = *(_Float16*)&u;
  return (float)h;
}
__device__ __forceinline__ unsigned short f2h(float f) {
  _Float16 h = (_Float16)f;
  return *(unsigned short*)&h;
}
__device__ __forceinline__ unsigned int packh2(float lo, float hi) {
  return (unsigned int)f2h(lo) | ((unsigned int)f2h(hi) << 16);
}

// ------------------------------------------- atom encoder (slice-major h16)
__global__ __launch_bounds__(256) void atom_encode_k(
    const int* __restrict__ nfeat, const float* __restrict__ atom_emb,
    unsigned short* __restrict__ h16)
{
  int w = threadIdx.x >> 6, lane = threadIdx.x & 63;
  int n = blockIdx.x * 4 + w;
  if (n >= N_NODESC) return;
  const int* nf = nfeat + n * 9;
  float ax = 0.f, ay = 0.f, az = 0.f, aw = 0.f;
#pragma unroll
  for (int c = 0; c < 9; ++c) {
    int idx = nf[c];
    const float4* row = (const float4*)(atom_emb + (c * 128 + idx) * EMBEDC);
    float4 v = row[lane];
    ax += v.x; ay += v.y; az += v.z; aw += v.w;
  }
  ushort4 o;
  o.x = f2h(ax); o.y = f2h(ay); o.z = f2h(az); o.w = f2h(aw);
  int col = lane * 4;
  *(ushort4*)(h16 + (long)(col >> 5) * SLAB + (long)n * 32 + (col & 31)) = o;
}

// ---------------------------------------------------------------- degree count
__global__ __launch_bounds__(256) void deg_k(
    const int* __restrict__ dst, int* __restrict__ degs)
{
  int e = blockIdx.x * 256 + threadIdx.x;
  if (e >= N_EDGESC) return;
  atomicAdd(&degs[dst[e]], 1);
}

// ------------------------------------------- parallel 3-phase exclusive scan
__global__ __launch_bounds__(256) void scan_partial_k(
    const int* __restrict__ deg, int* __restrict__ bsum)
{
  __shared__ int buf[256];
  int b = blockIdx.x, t = threadIdx.x;
  int idx0 = b * 1024 + t * 4;
  int s = 0;
#pragma unroll
  for (int i = 0; i < 4; ++i) {
    int idx = idx0 + i;
    if (idx < N_NODESC) s += deg[idx];
  }
  buf[t] = s;
  __syncthreads();
  for (int off = 1; off < 256; off <<= 1) {
    int add = (t >= off) ? buf[t - off] : 0;
    __syncthreads();
    buf[t] += add;
    __syncthreads();
  }
  if (t == 255) bsum[b] = buf[255];
}
__global__ __launch_bounds__(64) void scan_sums_k(
    const int* __restrict__ bsum, int* __restrict__ boff)
{
  __shared__ int buf[64];
  int t = threadIdx.x;
  int v = (t < 49) ? bsum[t] : 0;
  buf[t] = v;
  __syncthreads();
  for (int off = 1; off < 64; off <<= 1) {
    int add = (t >= off) ? buf[t - off] : 0;
    __syncthreads();
    buf[t] += add;
    __syncthreads();
  }
  if (t < 49) boff[t] = buf[t] - v;   // exclusive
  if (t == 48) boff[49] = buf[48];    // total
}
__global__ __launch_bounds__(256) void scan_final_k(
    const int* __restrict__ deg, const int* __restrict__ boff,
    int* __restrict__ row_start)
{
  __shared__ int buf[256];
  int b = blockIdx.x, t = threadIdx.x;
  int idx0 = b * 1024 + t * 4;
  int loc[4];
  int s = 0;
#pragma unroll
  for (int i = 0; i < 4; ++i) {
    int idx = idx0 + i;
    int v = (idx < N_NODESC) ? deg[idx] : 0;
    loc[i] = v; s += v;
  }
  buf[t] = s;
  __syncthreads();
  for (int off = 1; off < 256; off <<= 1) {
    int add = (t >= off) ? buf[t - off] : 0;
    __syncthreads();
    buf[t] += add;
    __syncthreads();
  }
  int run = boff[b] + buf[t] - s;
#pragma unroll
  for (int i = 0; i < 4; ++i) {
    int idx = idx0 + i;
    if (idx < N_NODESC) row_start[idx] = run;
    run += loc[i];
  }
  if (b == 48 && t == 255) row_start[N_NODESC] = boff[49];
}

// ----------------- degree-sorted node permutation (counting sort, 64 bins)
__global__ __launch_bounds__(256) void dhist_k(
    const int* __restrict__ row_start, int* __restrict__ dhist)
{
  int n = blockIdx.x * 256 + threadIdx.x;
  if (n >= N_NODESC) return;
  int d = row_start[n + 1] - row_start[n];
  atomicAdd(&dhist[d < 63 ? d : 63], 1);
}
__global__ __launch_bounds__(64) void dscan_k(
    const int* __restrict__ dhist, int* __restrict__ doff)
{
  __shared__ int buf[64];
  int t = threadIdx.x;
  int v = dhist[t];
  buf[t] = v;
  __syncthreads();
  for (int off = 1; off < 64; off <<= 1) {
    int add = (t >= off) ? buf[t - off] : 0;
    __syncthreads();
    buf[t] += add;
    __syncthreads();
  }
  doff[t] = buf[t] - v;   // exclusive; used as running fill counters
}
__global__ __launch_bounds__(256) void dfill_k(
    const int* __restrict__ row_start, int* __restrict__ doff,
    int* __restrict__ nperm)
{
  int n = blockIdx.x * 256 + threadIdx.x;
  if (n >= N_NODESC) return;
  int d = row_start[n + 1] - row_start[n];
  int pos = atomicAdd(&doff[d < 63 ? d : 63], 1);
  nperm[pos] = n;
}

// ------------------------------------ CSR scatter, range-partitioned by dst
__global__ __launch_bounds__(256) void scatter_k(
    const int* __restrict__ src, const int* __restrict__ dst,
    const int* __restrict__ row_start, int* __restrict__ fill,
    int* __restrict__ csrc, int* __restrict__ ceid)
{
  int b = blockIdx.x;
  int r = b & 7;
  int e = (b >> 3) * 256 + threadIdx.x;
  if (e >= N_EDGESC) return;
  int d = dst[e];
  int lo = r * NRANGE;
  if (d < lo || d >= lo + NRANGE) return;
  int pos = row_start[d] + atomicAdd(&fill[d], 1);
  csrc[pos] = src[e];
  ceid[pos] = e;
}

// ------------------- per-node edge-feature histogram -> fp16 cnt/(deg+1)
__global__ __launch_bounds__(256) void cntf_k(
    const int* __restrict__ ceid, const int* __restrict__ row_start,
    const int* __restrict__ efeat, unsigned short* __restrict__ cntf)
{
  __shared__ int lc[256 * 25];
  int t = threadIdx.x;
  int n = blockIdx.x * 256 + t;          // 196*256 == 50176 == N_PAD
  int base = t * 25;
#pragma unroll
  for (int j = 0; j < 24; ++j) lc[base + j] = 0;
  float inv = 0.f;
  if (n < N_NODESC) {
    int s0 = row_start[n], s1 = row_start[n + 1];
    inv = 1.0f / (float)(s1 - s0 + 1);
    for (int e = s0; e < s1; ++e) {
      int eid = ceid[e];
      int v0 = efeat[eid * 3 + 0];
      int v1 = efeat[eid * 3 + 1];
      int v2 = efeat[eid * 3 + 2];
      lc[base + v0]++;
      lc[base + 8 + v1]++;
      lc[base + 16 + v2]++;
    }
  }
  unsigned int* o = (unsigned int*)(cntf + (long)n * 32);
#pragma unroll
  for (int j = 0; j < 12; ++j)
    o[j] = packh2((float)lc[base + 2 * j] * inv, (float)lc[base + 2 * j + 1] * inv);
#pragma unroll
  for (int j = 12; j < 16; ++j) o[j] = 0u;
}

// ------------------------------------------------ W transpose + fp16 convert
__global__ __launch_bounds__(256) void wprep_k(
    const float* __restrict__ W, unsigned short* __restrict__ Wt)
{
  int tid = blockIdx.x * 256 + threadIdx.x;     // 5*65536
  int l = tid >> 16, r = tid & 65535;
  int n = r >> 8, k = r & 255;
  float w = W[(long)l * 65536 + k * 256 + n];
  Wt[tid] = f2h(w);                             // tid == l*65536 + n*256 + k
}

// ------------------------------ EW[l] = E[l] @ W[l], stored transposed [c'][32]
__global__ __launch_bounds__(256) void ew_k(
    const float* __restrict__ edge_emb, const float* __restrict__ W,
    unsigned short* __restrict__ EWt)
{
  __shared__ float e[256];
  int l = blockIdx.x / 24, j = blockIdx.x % 24;
  int c = threadIdx.x;
  e[c] = edge_emb[(long)l * 6144 + j * 256 + c];
  __syncthreads();
  const float* Wl = W + (long)l * 65536;
  float acc = 0.f;
#pragma unroll 8
  for (int k = 0; k < 256; ++k) acc += e[k] * Wl[k * 256 + c];
  EWt[((long)l * 256 + c) * 32 + j] = f2h(acc);
}

// ---------------------------------------------------------------- aggregation
// XCD-sliced (slice = blockIdx%8 -> slab L2-resident per XCD). Wave = 8 nodes
// x 8 lanes (2 edge-groups x 4 chunks of 16B), nodes taken in degree-sorted
// order (nperm) so wave lanes have near-uniform trip counts. 4 gathers in
// flight per lane. Packed fp16 accumulate, single fp32 flush.
template<int FUSE_BN>
__device__ __forceinline__ hf8 bnval(const uint4 u, const hf8 scv, const hf8 shv)
{
  union { uint4 u4; hf8 h8; } cv;
  cv.u4 = u;
  hf8 y = cv.h8;
  if (FUSE_BN) {
    y = y * scv + shv;                        // v_pk_fma_f16 x4
    y = __builtin_elementwise_max(y, (hf8)0); // v_pk_max_f16 x4
  }
  return y;
}

template<int FUSE_BN>
__global__ __launch_bounds__(256) void aggregate_t(
    const unsigned short* __restrict__ tab_base,
    const int* __restrict__ csrc, const int* __restrict__ row_start,
    const int* __restrict__ nperm,
    const unsigned short* __restrict__ sc16,
    const unsigned short* __restrict__ sh16,
    unsigned short* __restrict__ X16)
{
  int bid = blockIdx.x;
  int s = bid & 7;                               // slice == XCD (heuristic)
  int grp = bid >> 3;
  int lane = threadIdx.x & 63;
  int w = threadIdx.x >> 6;
  int nd = lane >> 3;            // node slot within wave (8)
  int g = (lane >> 2) & 1;       // edge group (2)
  int q = lane & 3;              // 16B chunk (4)
  int gidx = grp * 32 + w * 8 + nd;
  if (gidx >= N_NODESC) return;
  int n = nperm[gidx];           // degree-sorted node id
  const unsigned short* tab = tab_base + (long)s * SLAB;
  hf8 scv = (hf8)0, shv = (hf8)0;
  if (FUSE_BN) {
    scv = *(const hf8*)(sc16 + s * 32 + q * 8);
    shv = *(const hf8*)(sh16 + s * 32 + q * 8);
  }
  int s0 = row_start[n], s1 = row_start[n + 1];
  hf8 hacc = (hf8)0;                             // packed fp16 accumulator
  if (g == 0) {                                  // self row (once, pre-reduce)
    uint4 u = *(const uint4*)(tab + (long)n * 32 + q * 8);
    hacc = hacc + bnval<FUSE_BN>(u, scv, shv);
  }
  int e = s0 + g;
  for (; e + 6 < s1; e += 8) {                   // 4 edges in flight per lane
    int i0 = csrc[e];
    int i1 = csrc[e + 2];
    int i2 = csrc[e + 4];
    int i3 = csrc[e + 6];
    uint4 u0 = *(const uint4*)(tab + (long)i0 * 32 + q * 8);
    uint4 u1 = *(const uint4*)(tab + (long)i1 * 32 + q * 8);
    uint4 u2 = *(const uint4*)(tab + (long)i2 * 32 + q * 8);
    uint4 u3 = *(const uint4*)(tab + (long)i3 * 32 + q * 8);
    hacc = hacc + bnval<FUSE_BN>(u0, scv, shv);
    hacc = hacc + bnval<FUSE_BN>(u1, scv, shv);
    hacc = hacc + bnval<FUSE_BN>(u2, scv, shv);
    hacc = hacc + bnval<FUSE_BN>(u3, scv, shv);
  }
  for (; e < s1; e += 2) {
    int i0 = csrc[e];
    uint4 u = *(const uint4*)(tab + (long)i0 * 32 + q * 8);
    hacc = hacc + bnval<FUSE_BN>(u, scv, shv);
  }
  // fp32 flush, then reduce over the 2 edge-groups (lane bit 2)
  float a[8];
#pragma unroll
  for (int k = 0; k < 8; ++k) a[k] = (float)hacc[k];
#pragma unroll
  for (int k = 0; k < 8; ++k) a[k] += __shfl_xor(a[k], 4);
  if (g == 0) {                                  // 4 lanes/node write 64B
    float inv = 1.0f / (float)(s1 - s0 + 1);
    uint4 o;
    o.x = packh2(a[0] * inv, a[1] * inv);
    o.y = packh2(a[2] * inv, a[3] * inv);
    o.z = packh2(a[4] * inv, a[5] * inv);
    o.w = packh2(a[6] * inv, a[7] * inv);
    *(uint4*)(X16 + (long)s * SLAB + (long)n * 32 + q * 8) = o;
  }
}

// ---------------------------------------------------------------- MFMA GEMM fp16
// Y16 = fp16([X | cntf] @ [W ; EW] + b), K = 256 + 32(24 used).
__global__ __launch_bounds__(256) void gemm_k(
    const unsigned short* __restrict__ X16, const unsigned short* __restrict__ Bt,
    const unsigned short* __restrict__ cntf, const unsigned short* __restrict__ EWt,
    const float* __restrict__ bl, unsigned short* __restrict__ Y16,
    float* __restrict__ Pp)
{
  __shared__ unsigned short As[128 * 72];
  __shared__ unsigned short Bs[128 * 72];
  __shared__ float red_s[256];
  __shared__ float red_q[256];

  int t = threadIdx.x;
  int bm = blockIdx.x, bn = blockIdx.y;
  int row0 = bm * 128, nc0 = bn * 128;
  int w = t >> 6, l = t & 63;
  int wr = w >> 1, wc = w & 1;
  int lr = l & 15, lk = l >> 4;

  fx4 acc[4][4];
#pragma unroll
  for (int i = 0; i < 4; ++i)
#pragma unroll
    for (int j = 0; j < 4; ++j) acc[i][j] = (fx4){0.f, 0.f, 0.f, 0.f};

  for (int kb = 0; kb < 5; ++kb) {
    __syncthreads();
    if (kb < 4) {
      int kc = kb * 64;
#pragma unroll
      for (int q = 0; q < 2; ++q) {
        int id = q * 256 + t;
        int r = id >> 2, c16 = (id & 3) << 4;
        int ktot = kc + c16;
        long gA = (long)(ktot >> 5) * SLAB + (long)(row0 + r) * 32 + (ktot & 31);
        long gB = (long)(nc0 + r) * 256 + ktot;
        *(uint4*)&As[r * 72 + c16] = *(const uint4*)(X16 + gA);
        *(uint4*)&As[r * 72 + c16 + 8] = *(const uint4*)(X16 + gA + 8);
        *(uint4*)&Bs[r * 72 + c16] = *(const uint4*)(Bt + gB);
        *(uint4*)&Bs[r * 72 + c16 + 8] = *(const uint4*)(Bt + gB + 8);
      }
    } else {
#pragma unroll
      for (int q = 0; q < 2; ++q) {
        int id = q * 256 + t;
        int r = id >> 2, c8 = (id & 3) << 3;
        *(uint4*)&As[r * 72 + c8] = *(const uint4*)(cntf + (long)(row0 + r) * 32 + c8);
        *(uint4*)&Bs[r * 72 + c8] = *(const uint4*)(EWt + (long)(nc0 + r) * 32 + c8);
      }
    }
    __syncthreads();
    int nks = (kb < 4) ? 2 : 1;
    for (int ks = 0; ks < nks; ++ks) {
      int ko = ks * 32 + lk * 8;
      hf8 af[4], bf[4];
#pragma unroll
      for (int f = 0; f < 4; ++f) {
        af[f] = *(const hf8*)&As[(wr * 64 + f * 16 + lr) * 72 + ko];
        bf[f] = *(const hf8*)&Bs[(wc * 64 + f * 16 + lr) * 72 + ko];
      }
#pragma unroll
      for (int fm = 0; fm < 4; ++fm)
#pragma unroll
        for (int fn = 0; fn < 4; ++fn)
          acc[fm][fn] = __builtin_amdgcn_mfma_f32_16x16x32_f16(
              af[fm], bf[fn], acc[fm][fn], 0, 0, 0);
    }
  }

  float bcol[4];
#pragma unroll
  for (int fn = 0; fn < 4; ++fn) bcol[fn] = bl[nc0 + wc * 64 + fn * 16 + lr];
  float sp[4] = {0.f, 0.f, 0.f, 0.f}, qp[4] = {0.f, 0.f, 0.f, 0.f};
#pragma unroll
  for (int fm = 0; fm < 4; ++fm)
#pragma unroll
    for (int fn = 0; fn < 4; ++fn) {
      int cl = wc * 64 + fn * 16 + lr;
      int col = nc0 + cl;
      long ybase = (long)(col >> 5) * SLAB + (col & 31);
#pragma unroll
      for (int j = 0; j < 4; ++j) {
        int rl = wr * 64 + fm * 16 + lk * 4 + j;
        float v = acc[fm][fn][j] + bcol[fn];
        Y16[ybase + (long)(row0 + rl) * 32] = f2h(v);
        sp[fn] += v; qp[fn] += v * v;
      }
    }
#pragma unroll
  for (int fn = 0; fn < 4; ++fn) {
    sp[fn] += __shfl_xor(sp[fn], 16);
    sp[fn] += __shfl_xor(sp[fn], 32);
    qp[fn] += __shfl_xor(qp[fn], 16);
    qp[fn] += __shfl_xor(qp[fn], 32);
  }
  if (lk == 0) {
#pragma unroll
    for (int fn = 0; fn < 4; ++fn) {
      red_s[w * 64 + fn * 16 + lr] = sp[fn];
      red_q[w * 64 + fn * 16 + lr] = qp[fn];
    }
  }
  __syncthreads();
  if (t < 128) {
    float s = red_s[t] + red_s[128 + t];
    float q = red_q[t] + red_q[128 + t];
    float* p = Pp + (bm * 2 + bn) * 256;
    p[t] = s;
    p[128 + t] = q;
  }
}

// --------------------------- BN stats reduce + finalize (256 blocks, parallel)
__global__ __launch_bounds__(128) void stats_finalize_k(
    const float* __restrict__ Pp, const float* __restrict__ bl,
    const float* __restrict__ gamma, const float* __restrict__ beta,
    float* __restrict__ scale, float* __restrict__ shiftv,
    unsigned short* __restrict__ sc16, unsigned short* __restrict__ sh16)
{
  __shared__ float red_s[128];
  __shared__ float red_q[128];
  int c = blockIdx.x;                 // one column per block
  int half = c >> 7, cl = c & 127;
  int t = threadIdx.x;
  float s = 0.f, q = 0.f;
  for (int bm = t; bm < MTILES; bm += 128) {
    const float* p = Pp + (bm * 2 + half) * 256;
    s += p[cl];
    q += p[128 + cl];
  }
  red_s[t] = s; red_q[t] = q;
  __syncthreads();
#pragma unroll
  for (int off = 64; off > 0; off >>= 1) {
    if (t < off) {
      red_s[t] += red_s[t + off];
      red_q[t] += red_q[t + off];
    }
    __syncthreads();
  }
  if (t == 0) {
    s = red_s[0]; q = red_q[0];
    float bc = bl[c];
    s -= (float)(N_PAD - N_NODESC) * bc;
    q -= (float)(N_PAD - N_NODESC) * bc * bc;
    const float invN = 1.0f / (float)N_NODESC;
    float mu = s * invN;
    float var = q * invN - mu * mu;
    float rsq = rsqrtf(var + 1e-5f);
    float sc = gamma[c] * rsq;
    float sh = beta[c] - mu * sc;
    scale[c] = sc;
    shiftv[c] = sh;
    sc16[c] = f2h(sc);
    sh16[c] = f2h(sh);
  }
}

// ---------------------------------------------------------------- mean pooling
__device__ __forceinline__ int lower_bound_g(const int* gid, int n, int g)
{
  int lo = 0, hi = n;
  while (lo < hi) {
    int mid = (lo + hi) >> 1;
    if (gid[mid] < g) lo = mid + 1; else hi = mid;
  }
  return lo;
}

__global__ __launch_bounds__(512) void pool_k(
    const unsigned short* __restrict__ Y16, const int* __restrict__ gid,
    const float* __restrict__ scale, const float* __restrict__ shiftv,
    float* __restrict__ gpool)
{
  __shared__ float red[8 * 256];
  int g = blockIdx.x;
  int lo = lower_bound_g(gid, N_NODESC, g);
  int hi = lower_bound_g(gid, N_NODESC, g + 1);
  int t = threadIdx.x;
  int w = t >> 6, lane = t & 63;
  int col = lane * 4;
  long ybase = (long)(col >> 5) * SLAB + (col & 31);
  float4 sc = *(const float4*)(scale + col);
  float4 sh = *(const float4*)(shiftv + col);
  float a0 = 0.f, a1 = 0.f, a2 = 0.f, a3 = 0.f;
  for (int r = lo + w; r < hi; r += 8) {
    ushort4 u = *(const ushort4*)(Y16 + ybase + (long)r * 32);
    a0 += fmaxf(0.f, h2f(u.x) * sc.x + sh.x);
    a1 += fmaxf(0.f, h2f(u.y) * sc.y + sh.y);
    a2 += fmaxf(0.f, h2f(u.z) * sc.z + sh.z);
    a3 += fmaxf(0.f, h2f(u.w) * sc.w + sh.w);
  }
  *(float4*)&red[w * 256 + col] = make_float4(a0, a1, a2, a3);
  __syncthreads();
  if (t < 256) {
    float s = 0.f;
#pragma unroll
    for (int j = 0; j < 8; ++j) s += red[j * 256 + t];
    int c = hi - lo;
    gpool[g * 256 + t] = s / (float)(c > 0 ? c : 1);
  }
}

// ---------------------------------------------------------------- final proj
__global__ __launch_bounds__(128) void final_k(
    const float* __restrict__ gpool, const float* __restrict__ Wp,
    const float* __restrict__ bp, float* __restrict__ out)
{
  __shared__ float gr[256];
  int g = blockIdx.x, t = threadIdx.x;
  gr[t] = gpool[g * 256 + t];
  gr[t + 128] = gpool[g * 256 + t + 128];
  __syncthreads();
  float acc = bp[t];
#pragma unroll 8
  for (int k = 0; k < 256; ++k) acc += gr[k] * Wp[k * 128 + t];
  out[g * 128 + t] = acc;
}

// ---------------------------------------------------------------- launcher
extern "C" void kernel_launch(void* const* d_in, const int* in_sizes, int n_in,
                              void* d_out, int out_size, void* d_ws, size_t ws_size,
                              hipStream_t stream)
{
  (void)in_sizes; (void)n_in; (void)out_size; (void)ws_size;
  const int* nfeat = (const int*)d_in[0];
  const int* efeat = (const int*)d_in[1];
  const int* src = (const int*)d_in[2];
  const int* dst = (const int*)d_in[3];
  const int* gid = (const int*)d_in[4];
  const float* atom_emb = (const float*)d_in[5];
  const float* edge_emb = (const float*)d_in[6];
  const float* W = (const float*)d_in[7];
  const float* b = (const float*)d_in[8];
  const float* gamma = (const float*)d_in[9];
  const float* beta = (const float*)d_in[10];
  const float* Wp = (const float*)d_in[11];
  const float* bp = (const float*)d_in[12];
  float* out = (float*)d_out;

  char* ws = (char*)d_ws;
  unsigned short* h16 = (unsigned short*)ws; ws += (size_t)N_PAD * 512;
  unsigned short* Y16 = (unsigned short*)ws; ws += (size_t)N_PAD * 512;
  unsigned short* X16 = (unsigned short*)ws; ws += (size_t)N_PAD * 512;
  unsigned short* Wt = (unsigned short*)ws; ws += 5 * 65536 * 2;
  unsigned short* EWt = (unsigned short*)ws; ws += 5 * 256 * 32 * 2;
  unsigned short* cntf = (unsigned short*)ws; ws += (size_t)N_PAD * 32 * 2;
  int* csrc = (int*)ws; ws += 3200000;
  int* ceid = (int*)ws; ws += 3200000;
  int* row_start = (int*)ws; ws += 200064;
  int* degs_i = (int*)ws; ws += 200064;
  int* fill = (int*)ws; ws += 200064;
  int* nperm = (int*)ws; ws += 200064;
  int* bsum = (int*)ws; ws += 256;
  int* boff = (int*)ws; ws += 256;
  int* dhist = (int*)ws; ws += 256;
  int* doff = (int*)ws; ws += 256;
  float* Pp = (float*)ws; ws += MTILES * 2 * 256 * 4;
  float* scale = (float*)ws; ws += 1024;
  float* shiftv = (float*)ws; ws += 1024;
  unsigned short* sc16 = (unsigned short*)ws; ws += 512;
  unsigned short* sh16 = (unsigned short*)ws; ws += 512;
  float* gpool = (float*)ws; ws += 131072;

  hipMemsetAsync(degs_i, 0, 200000, stream);
  hipMemsetAsync(fill, 0, 200000, stream);
  hipMemsetAsync(dhist, 0, 256, stream);
  // zero X16 pad rows in each slice slab so GEMM pad output is exactly b[c]
  for (int s = 0; s < 8; ++s)
    hipMemsetAsync(X16 + (size_t)s * SLAB + (size_t)N_NODESC * 32, 0,
                   (size_t)(N_PAD - N_NODESC) * 64, stream);

  wprep_k<<<1280, 256, 0, stream>>>(W, Wt);
  ew_k<<<120, 256, 0, stream>>>(edge_emb, W, EWt);
  atom_encode_k<<<12500, 256, 0, stream>>>(nfeat, atom_emb, h16);
  deg_k<<<3125, 256, 0, stream>>>(dst, degs_i);
  scan_partial_k<<<49, 256, 0, stream>>>(degs_i, bsum);
  scan_sums_k<<<1, 64, 0, stream>>>(bsum, boff);
  scan_final_k<<<49, 256, 0, stream>>>(degs_i, boff, row_start);
  dhist_k<<<196, 256, 0, stream>>>(row_start, dhist);
  dscan_k<<<1, 64, 0, stream>>>(dhist, doff);
  dfill_k<<<196, 256, 0, stream>>>(row_start, doff, nperm);
  scatter_k<<<25000, 256, 0, stream>>>(src, dst, row_start, fill, csrc, ceid);
  cntf_k<<<196, 256, 0, stream>>>(ceid, row_start, efeat, cntf);

  // layer 0 aggregate: atom-encoded h16, no BN
  aggregate_t<0><<<12504, 256, 0, stream>>>(h16, csrc, row_start, nperm,
                                            nullptr, nullptr, X16);
  for (int l = 0; l < 5; ++l) {
    gemm_k<<<dim3(MTILES, 2), 256, 0, stream>>>(X16, Wt + l * 65536, cntf,
                                                EWt + l * 8192, b + l * 256,
                                                Y16, Pp);
    stats_finalize_k<<<256, 128, 0, stream>>>(Pp, b + l * 256, gamma + l * 256,
                                              beta + l * 256, scale, shiftv,
                                              sc16, sh16);
    if (l < 4)
      aggregate_t<1><<<12504, 256, 0, stream>>>(Y16, csrc, row_start, nperm,
                                                sc16, sh16, X16);
  }

  pool_k<<<128, 512, 0, stream>>>(Y16, gid, scale, shiftv, gpool);
  final_k<<<128, 128, 0, stream>>>(gpool, Wp, bp, out);
}

// Round 20
// 560.275 us; speedup vs baseline: 1.5534x; 1.5534x over previous
//
#include <hip/hip_runtime.h>

#define N_NODESC 50000
#define N_PAD 50176          // 392 * 128
#define N_EDGESC 800000
#define N_GRAPHSC 128
#define EMBEDC 256
#define MTILES 392
#define SLAB ((long)N_PAD * 32)   // halves per 32-col slice slab
#define NRANGE 6272               // N_PAD/8: node range per scatter slice

typedef __attribute__((ext_vector_type(8))) _Float16 hf8;
typedef __attribute__((ext_vector_type(4))) float fx4;

__device__ __forceinline__ float h2f(unsigned short u) {
  _Float16 h = *(_Float16*)&u;
  return (float)h;
}
__device__ __forceinline__ unsigned short f2h(float f) {
  _Float16 h = (_Float16)f;
  return *(unsigned short*)&h;
}
__device__ __forceinline__ unsigned int packh2(float lo, float hi) {
  return (unsigned int)f2h(lo) | ((unsigned int)f2h(hi) << 16);
}

// ------------------------------------------- atom encoder (slice-major h16)
__global__ __launch_bounds__(256) void atom_encode_k(
    const int* __restrict__ nfeat, const float* __restrict__ atom_emb,
    unsigned short* __restrict__ h16)
{
  int w = threadIdx.x >> 6, lane = threadIdx.x & 63;
  int n = blockIdx.x * 4 + w;
  if (n >= N_NODESC) return;
  const int* nf = nfeat + n * 9;
  float ax = 0.f, ay = 0.f, az = 0.f, aw = 0.f;
#pragma unroll
  for (int c = 0; c < 9; ++c) {
    int idx = nf[c];
    const float4* row = (const float4*)(atom_emb + (c * 128 + idx) * EMBEDC);
    float4 v = row[lane];
    ax += v.x; ay += v.y; az += v.z; aw += v.w;
  }
  ushort4 o;
  o.x = f2h(ax); o.y = f2h(ay); o.z = f2h(az); o.w = f2h(aw);
  int col = lane * 4;
  *(ushort4*)(h16 + (long)(col >> 5) * SLAB + (long)n * 32 + (col & 31)) = o;
}

// ---------------------------------------------------------------- degree count
__global__ __launch_bounds__(256) void deg_k(
    const int* __restrict__ dst, int* __restrict__ degs)
{
  int e = blockIdx.x * 256 + threadIdx.x;
  if (e >= N_EDGESC) return;
  atomicAdd(&degs[dst[e]], 1);
}

// ------------------------------------------- parallel 3-phase exclusive scan
__global__ __launch_bounds__(256) void scan_partial_k(
    const int* __restrict__ deg, int* __restrict__ bsum)
{
  __shared__ int buf[256];
  int b = blockIdx.x, t = threadIdx.x;
  int idx0 = b * 1024 + t * 4;
  int s = 0;
#pragma unroll
  for (int i = 0; i < 4; ++i) {
    int idx = idx0 + i;
    if (idx < N_NODESC) s += deg[idx];
  }
  buf[t] = s;
  __syncthreads();
  for (int off = 1; off < 256; off <<= 1) {
    int add = (t >= off) ? buf[t - off] : 0;
    __syncthreads();
    buf[t] += add;
    __syncthreads();
  }
  if (t == 255) bsum[b] = buf[255];
}
__global__ __launch_bounds__(64) void scan_sums_k(
    const int* __restrict__ bsum, int* __restrict__ boff)
{
  __shared__ int buf[64];
  int t = threadIdx.x;
  int v = (t < 49) ? bsum[t] : 0;
  buf[t] = v;
  __syncthreads();
  for (int off = 1; off < 64; off <<= 1) {
    int add = (t >= off) ? buf[t - off] : 0;
    __syncthreads();
    buf[t] += add;
    __syncthreads();
  }
  if (t < 49) boff[t] = buf[t] - v;   // exclusive
  if (t == 48) boff[49] = buf[48];    // total
}
__global__ __launch_bounds__(256) void scan_final_k(
    const int* __restrict__ deg, const int* __restrict__ boff,
    int* __restrict__ row_start)
{
  __shared__ int buf[256];
  int b = blockIdx.x, t = threadIdx.x;
  int idx0 = b * 1024 + t * 4;
  int loc[4];
  int s = 0;
#pragma unroll
  for (int i = 0; i < 4; ++i) {
    int idx = idx0 + i;
    int v = (idx < N_NODESC) ? deg[idx] : 0;
    loc[i] = v; s += v;
  }
  buf[t] = s;
  __syncthreads();
  for (int off = 1; off < 256; off <<= 1) {
    int add = (t >= off) ? buf[t - off] : 0;
    __syncthreads();
    buf[t] += add;
    __syncthreads();
  }
  int run = boff[b] + buf[t] - s;
#pragma unroll
  for (int i = 0; i < 4; ++i) {
    int idx = idx0 + i;
    if (idx < N_NODESC) row_start[idx] = run;
    run += loc[i];
  }
  if (b == 48 && t == 255) row_start[N_NODESC] = boff[49];
}

// ------------------------------------ CSR scatter, range-partitioned by dst
__global__ __launch_bounds__(256) void scatter_k(
    const int* __restrict__ src, const int* __restrict__ dst,
    const int* __restrict__ row_start, int* __restrict__ fill,
    int* __restrict__ csrc, int* __restrict__ ceid)
{
  int b = blockIdx.x;
  int r = b & 7;
  int e = (b >> 3) * 256 + threadIdx.x;
  if (e >= N_EDGESC) return;
  int d = dst[e];
  int lo = r * NRANGE;
  if (d < lo || d >= lo + NRANGE) return;
  int pos = row_start[d] + atomicAdd(&fill[d], 1);
  csrc[pos] = src[e];
  ceid[pos] = e;
}

// ------------------- per-node edge-feature histogram -> fp16 cnt/(deg+1)
__global__ __launch_bounds__(256) void cntf_k(
    const int* __restrict__ ceid, const int* __restrict__ row_start,
    const int* __restrict__ efeat, unsigned short* __restrict__ cntf)
{
  __shared__ int lc[256 * 25];
  int t = threadIdx.x;
  int n = blockIdx.x * 256 + t;          // 196*256 == 50176 == N_PAD
  int base = t * 25;
#pragma unroll
  for (int j = 0; j < 24; ++j) lc[base + j] = 0;
  float inv = 0.f;
  if (n < N_NODESC) {
    int s0 = row_start[n], s1 = row_start[n + 1];
    inv = 1.0f / (float)(s1 - s0 + 1);
    for (int e = s0; e < s1; ++e) {
      int eid = ceid[e];
      int v0 = efeat[eid * 3 + 0];
      int v1 = efeat[eid * 3 + 1];
      int v2 = efeat[eid * 3 + 2];
      lc[base + v0]++;
      lc[base + 8 + v1]++;
      lc[base + 16 + v2]++;
    }
  }
  unsigned int* o = (unsigned int*)(cntf + (long)n * 32);
#pragma unroll
  for (int j = 0; j < 12; ++j)
    o[j] = packh2((float)lc[base + 2 * j] * inv, (float)lc[base + 2 * j + 1] * inv);
#pragma unroll
  for (int j = 12; j < 16; ++j) o[j] = 0u;
}

// ------------------------------------------------ W transpose + fp16 convert
__global__ __launch_bounds__(256) void wprep_k(
    const float* __restrict__ W, unsigned short* __restrict__ Wt)
{
  int tid = blockIdx.x * 256 + threadIdx.x;     // 5*65536
  int l = tid >> 16, r = tid & 65535;
  int n = r >> 8, k = r & 255;
  float w = W[(long)l * 65536 + k * 256 + n];
  Wt[tid] = f2h(w);                             // tid == l*65536 + n*256 + k
}

// ------------------------------ EW[l] = E[l] @ W[l], stored transposed [c'][32]
__global__ __launch_bounds__(256) void ew_k(
    const float* __restrict__ edge_emb, const float* __restrict__ W,
    unsigned short* __restrict__ EWt)
{
  __shared__ float e[256];
  int l = blockIdx.x / 24, j = blockIdx.x % 24;
  int c = threadIdx.x;
  e[c] = edge_emb[(long)l * 6144 + j * 256 + c];
  __syncthreads();
  const float* Wl = W + (long)l * 65536;
  float acc = 0.f;
#pragma unroll 8
  for (int k = 0; k < 256; ++k) acc += e[k] * Wl[k * 256 + c];
  EWt[((long)l * 256 + c) * 32 + j] = f2h(acc);
}

// ---------------------------------------------------------------- aggregation
// XCD-sliced (slice = blockIdx%8 -> slab L2-resident per XCD). Wave = 8 nodes
// x 8 lanes (2 edge-groups x 4 chunks of 16B); 4 gathers in flight per lane.
// Packed fp16 accumulate, single fp32 flush. Histogram folded into GEMM.
template<int FUSE_BN>
__device__ __forceinline__ hf8 bnval(const uint4 u, const hf8 scv, const hf8 shv)
{
  union { uint4 u4; hf8 h8; } cv;
  cv.u4 = u;
  hf8 y = cv.h8;
  if (FUSE_BN) {
    y = y * scv + shv;                        // v_pk_fma_f16 x4
    y = __builtin_elementwise_max(y, (hf8)0); // v_pk_max_f16 x4
  }
  return y;
}

template<int FUSE_BN>
__global__ __launch_bounds__(256) void aggregate_t(
    const unsigned short* __restrict__ tab_base,
    const int* __restrict__ csrc, const int* __restrict__ row_start,
    const unsigned short* __restrict__ sc16,
    const unsigned short* __restrict__ sh16,
    unsigned short* __restrict__ X16)
{
  int bid = blockIdx.x;
  int s = bid & 7;                               // slice == XCD (heuristic)
  int grp = bid >> 3;
  int lane = threadIdx.x & 63;
  int w = threadIdx.x >> 6;
  int nd = lane >> 3;            // node within wave (8)
  int g = (lane >> 2) & 1;       // edge group (2)
  int q = lane & 3;              // 16B chunk (4)
  int n = grp * 32 + w * 8 + nd; // 1563 grps * 32 = 50016 >= 50000
  if (n >= N_NODESC) return;
  const unsigned short* tab = tab_base + (long)s * SLAB;
  hf8 scv = (hf8)0, shv = (hf8)0;
  if (FUSE_BN) {
    scv = *(const hf8*)(sc16 + s * 32 + q * 8);
    shv = *(const hf8*)(sh16 + s * 32 + q * 8);
  }
  int s0 = row_start[n], s1 = row_start[n + 1];
  hf8 hacc = (hf8)0;                             // packed fp16 accumulator
  if (g == 0) {                                  // self row (once, pre-reduce)
    uint4 u = *(const uint4*)(tab + (long)n * 32 + q * 8);
    hacc = hacc + bnval<FUSE_BN>(u, scv, shv);
  }
  int e = s0 + g;
  for (; e + 6 < s1; e += 8) {                   // 4 edges in flight per lane
    int i0 = csrc[e];
    int i1 = csrc[e + 2];
    int i2 = csrc[e + 4];
    int i3 = csrc[e + 6];
    uint4 u0 = *(const uint4*)(tab + (long)i0 * 32 + q * 8);
    uint4 u1 = *(const uint4*)(tab + (long)i1 * 32 + q * 8);
    uint4 u2 = *(const uint4*)(tab + (long)i2 * 32 + q * 8);
    uint4 u3 = *(const uint4*)(tab + (long)i3 * 32 + q * 8);
    hacc = hacc + bnval<FUSE_BN>(u0, scv, shv);
    hacc = hacc + bnval<FUSE_BN>(u1, scv, shv);
    hacc = hacc + bnval<FUSE_BN>(u2, scv, shv);
    hacc = hacc + bnval<FUSE_BN>(u3, scv, shv);
  }
  for (; e < s1; e += 2) {
    int i0 = csrc[e];
    uint4 u = *(const uint4*)(tab + (long)i0 * 32 + q * 8);
    hacc = hacc + bnval<FUSE_BN>(u, scv, shv);
  }
  // fp32 flush, then reduce over the 2 edge-groups (lane bit 2)
  float a[8];
#pragma unroll
  for (int k = 0; k < 8; ++k) a[k] = (float)hacc[k];
#pragma unroll
  for (int k = 0; k < 8; ++k) a[k] += __shfl_xor(a[k], 4);
  if (g == 0) {                                  // 4 lanes/node write 64B
    float inv = 1.0f / (float)(s1 - s0 + 1);
    uint4 o;
    o.x = packh2(a[0] * inv, a[1] * inv);
    o.y = packh2(a[2] * inv, a[3] * inv);
    o.z = packh2(a[4] * inv, a[5] * inv);
    o.w = packh2(a[6] * inv, a[7] * inv);
    *(uint4*)(X16 + (long)s * SLAB + (long)n * 32 + q * 8) = o;
  }
}

// ---------------------------------------------------------------- MFMA GEMM fp16
// Y16 = fp16([X | cntf] @ [W ; EW] + b), K = 256 + 32(24 used).
__global__ __launch_bounds__(256) void gemm_k(
    const unsigned short* __restrict__ X16, const unsigned short* __restrict__ Bt,
    const unsigned short* __restrict__ cntf, const unsigned short* __restrict__ EWt,
    const float* __restrict__ bl, unsigned short* __restrict__ Y16,
    float* __restrict__ Pp)
{
  __shared__ unsigned short As[128 * 72];
  __shared__ unsigned short Bs[128 * 72];
  __shared__ float red_s[256];
  __shared__ float red_q[256];

  int t = threadIdx.x;
  int bm = blockIdx.x, bn = blockIdx.y;
  int row0 = bm * 128, nc0 = bn * 128;
  int w = t >> 6, l = t & 63;
  int wr = w >> 1, wc = w & 1;
  int lr = l & 15, lk = l >> 4;

  fx4 acc[4][4];
#pragma unroll
  for (int i = 0; i < 4; ++i)
#pragma unroll
    for (int j = 0; j < 4; ++j) acc[i][j] = (fx4){0.f, 0.f, 0.f, 0.f};

  for (int kb = 0; kb < 5; ++kb) {
    __syncthreads();
    if (kb < 4) {
      int kc = kb * 64;
#pragma unroll
      for (int q = 0; q < 2; ++q) {
        int id = q * 256 + t;
        int r = id >> 2, c16 = (id & 3) << 4;
        int ktot = kc + c16;
        long gA = (long)(ktot >> 5) * SLAB + (long)(row0 + r) * 32 + (ktot & 31);
        long gB = (long)(nc0 + r) * 256 + ktot;
        *(uint4*)&As[r * 72 + c16] = *(const uint4*)(X16 + gA);
        *(uint4*)&As[r * 72 + c16 + 8] = *(const uint4*)(X16 + gA + 8);
        *(uint4*)&Bs[r * 72 + c16] = *(const uint4*)(Bt + gB);
        *(uint4*)&Bs[r * 72 + c16 + 8] = *(const uint4*)(Bt + gB + 8);
      }
    } else {
#pragma unroll
      for (int q = 0; q < 2; ++q) {
        int id = q * 256 + t;
        int r = id >> 2, c8 = (id & 3) << 3;
        *(uint4*)&As[r * 72 + c8] = *(const uint4*)(cntf + (long)(row0 + r) * 32 + c8);
        *(uint4*)&Bs[r * 72 + c8] = *(const uint4*)(EWt + (long)(nc0 + r) * 32 + c8);
      }
    }
    __syncthreads();
    int nks = (kb < 4) ? 2 : 1;
    for (int ks = 0; ks < nks; ++ks) {
      int ko = ks * 32 + lk * 8;
      hf8 af[4], bf[4];
#pragma unroll
      for (int f = 0; f < 4; ++f) {
        af[f] = *(const hf8*)&As[(wr * 64 + f * 16 + lr) * 72 + ko];
        bf[f] = *(const hf8*)&Bs[(wc * 64 + f * 16 + lr) * 72 + ko];
      }
#pragma unroll
      for (int fm = 0; fm < 4; ++fm)
#pragma unroll
        for (int fn = 0; fn < 4; ++fn)
          acc[fm][fn] = __builtin_amdgcn_mfma_f32_16x16x32_f16(
              af[fm], bf[fn], acc[fm][fn], 0, 0, 0);
    }
  }

  float bcol[4];
#pragma unroll
  for (int fn = 0; fn < 4; ++fn) bcol[fn] = bl[nc0 + wc * 64 + fn * 16 + lr];
  float sp[4] = {0.f, 0.f, 0.f, 0.f}, qp[4] = {0.f, 0.f, 0.f, 0.f};
#pragma unroll
  for (int fm = 0; fm < 4; ++fm)
#pragma unroll
    for (int fn = 0; fn < 4; ++fn) {
      int cl = wc * 64 + fn * 16 + lr;
      int col = nc0 + cl;
      long ybase = (long)(col >> 5) * SLAB + (col & 31);
#pragma unroll
      for (int j = 0; j < 4; ++j) {
        int rl = wr * 64 + fm * 16 + lk * 4 + j;
        float v = acc[fm][fn][j] + bcol[fn];
        Y16[ybase + (long)(row0 + rl) * 32] = f2h(v);
        sp[fn] += v; qp[fn] += v * v;
      }
    }
#pragma unroll
  for (int fn = 0; fn < 4; ++fn) {
    sp[fn] += __shfl_xor(sp[fn], 16);
    sp[fn] += __shfl_xor(sp[fn], 32);
    qp[fn] += __shfl_xor(qp[fn], 16);
    qp[fn] += __shfl_xor(qp[fn], 32);
  }
  if (lk == 0) {
#pragma unroll
    for (int fn = 0; fn < 4; ++fn) {
      red_s[w * 64 + fn * 16 + lr] = sp[fn];
      red_q[w * 64 + fn * 16 + lr] = qp[fn];
    }
  }
  __syncthreads();
  if (t < 128) {
    float s = red_s[t] + red_s[128 + t];
    float q = red_q[t] + red_q[128 + t];
    float* p = Pp + (bm * 2 + bn) * 256;
    p[t] = s;
    p[128 + t] = q;
  }
}

// --------------------------- BN stats reduce + finalize (256 blocks, parallel)
__global__ __launch_bounds__(128) void stats_finalize_k(
    const float* __restrict__ Pp, const float* __restrict__ bl,
    const float* __restrict__ gamma, const float* __restrict__ beta,
    float* __restrict__ scale, float* __restrict__ shiftv,
    unsigned short* __restrict__ sc16, unsigned short* __restrict__ sh16)
{
  __shared__ float red_s[128];
  __shared__ float red_q[128];
  int c = blockIdx.x;                 // one column per block
  int half = c >> 7, cl = c & 127;
  int t = threadIdx.x;
  float s = 0.f, q = 0.f;
  for (int bm = t; bm < MTILES; bm += 128) {
    const float* p = Pp + (bm * 2 + half) * 256;
    s += p[cl];
    q += p[128 + cl];
  }
  red_s[t] = s; red_q[t] = q;
  __syncthreads();
#pragma unroll
  for (int off = 64; off > 0; off >>= 1) {
    if (t < off) {
      red_s[t] += red_s[t + off];
      red_q[t] += red_q[t + off];
    }
    __syncthreads();
  }
  if (t == 0) {
    s = red_s[0]; q = red_q[0];
    float bc = bl[c];
    s -= (float)(N_PAD - N_NODESC) * bc;
    q -= (float)(N_PAD - N_NODESC) * bc * bc;
    const float invN = 1.0f / (float)N_NODESC;
    float mu = s * invN;
    float var = q * invN - mu * mu;
    float rsq = rsqrtf(var + 1e-5f);
    float sc = gamma[c] * rsq;
    float sh = beta[c] - mu * sc;
    scale[c] = sc;
    shiftv[c] = sh;
    sc16[c] = f2h(sc);
    sh16[c] = f2h(sh);
  }
}

// ---------------------------------------------------------------- mean pooling
__device__ __forceinline__ int lower_bound_g(const int* gid, int n, int g)
{
  int lo = 0, hi = n;
  while (lo < hi) {
    int mid = (lo + hi) >> 1;
    if (gid[mid] < g) lo = mid + 1; else hi = mid;
  }
  return lo;
}

__global__ __launch_bounds__(512) void pool_k(
    const unsigned short* __restrict__ Y16, const int* __restrict__ gid,
    const float* __restrict__ scale, const float* __restrict__ shiftv,
    float* __restrict__ gpool)
{
  __shared__ float red[8 * 256];
  int g = blockIdx.x;
  int lo = lower_bound_g(gid, N_NODESC, g);
  int hi = lower_bound_g(gid, N_NODESC, g + 1);
  int t = threadIdx.x;
  int w = t >> 6, lane = t & 63;
  int col = lane * 4;
  long ybase = (long)(col >> 5) * SLAB + (col & 31);
  float4 sc = *(const float4*)(scale + col);
  float4 sh = *(const float4*)(shiftv + col);
  float a0 = 0.f, a1 = 0.f, a2 = 0.f, a3 = 0.f;
  for (int r = lo + w; r < hi; r += 8) {
    ushort4 u = *(const ushort4*)(Y16 + ybase + (long)r * 32);
    a0 += fmaxf(0.f, h2f(u.x) * sc.x + sh.x);
    a1 += fmaxf(0.f, h2f(u.y) * sc.y + sh.y);
    a2 += fmaxf(0.f, h2f(u.z) * sc.z + sh.z);
    a3 += fmaxf(0.f, h2f(u.w) * sc.w + sh.w);
  }
  *(float4*)&red[w * 256 + col] = make_float4(a0, a1, a2, a3);
  __syncthreads();
  if (t < 256) {
    float s = 0.f;
#pragma unroll
    for (int j = 0; j < 8; ++j) s += red[j * 256 + t];
    int c = hi - lo;
    gpool[g * 256 + t] = s / (float)(c > 0 ? c : 1);
  }
}

// ---------------------------------------------------------------- final proj
__global__ __launch_bounds__(128) void final_k(
    const float* __restrict__ gpool, const float* __restrict__ Wp,
    const float* __restrict__ bp, float* __restrict__ out)
{
  __shared__ float gr[256];
  int g = blockIdx.x, t = threadIdx.x;
  gr[t] = gpool[g * 256 + t];
  gr[t + 128] = gpool[g * 256 + t + 128];
  __syncthreads();
  float acc = bp[t];
#pragma unroll 8
  for (int k = 0; k < 256; ++k) acc += gr[k] * Wp[k * 128 + t];
  out[g * 128 + t] = acc;
}

// ---------------------------------------------------------------- launcher
extern "C" void kernel_launch(void* const* d_in, const int* in_sizes, int n_in,
                              void* d_out, int out_size, void* d_ws, size_t ws_size,
                              hipStream_t stream)
{
  (void)in_sizes; (void)n_in; (void)out_size; (void)ws_size;
  const int* nfeat = (const int*)d_in[0];
  const int* efeat = (const int*)d_in[1];
  const int* src = (const int*)d_in[2];
  const int* dst = (const int*)d_in[3];
  const int* gid = (const int*)d_in[4];
  const float* atom_emb = (const float*)d_in[5];
  const float* edge_emb = (const float*)d_in[6];
  const float* W = (const float*)d_in[7];
  const float* b = (const float*)d_in[8];
  const float* gamma = (const float*)d_in[9];
  const float* beta = (const float*)d_in[10];
  const float* Wp = (const float*)d_in[11];
  const float* bp = (const float*)d_in[12];
  float* out = (float*)d_out;

  char* ws = (char*)d_ws;
  unsigned short* h16 = (unsigned short*)ws; ws += (size_t)N_PAD * 512;
  unsigned short* Y16 = (unsigned short*)ws; ws += (size_t)N_PAD * 512;
  unsigned short* X16 = (unsigned short*)ws; ws += (size_t)N_PAD * 512;
  unsigned short* Wt = (unsigned short*)ws; ws += 5 * 65536 * 2;
  unsigned short* EWt = (unsigned short*)ws; ws += 5 * 256 * 32 * 2;
  unsigned short* cntf = (unsigned short*)ws; ws += (size_t)N_PAD * 32 * 2;
  int* csrc = (int*)ws; ws += 3200000;
  int* ceid = (int*)ws; ws += 3200000;
  int* row_start = (int*)ws; ws += 200064;
  int* degs_i = (int*)ws; ws += 200064;
  int* fill = (int*)ws; ws += 200064;
  int* bsum = (int*)ws; ws += 256;
  int* boff = (int*)ws; ws += 256;
  float* Pp = (float*)ws; ws += MTILES * 2 * 256 * 4;
  float* scale = (float*)ws; ws += 1024;
  float* shiftv = (float*)ws; ws += 1024;
  unsigned short* sc16 = (unsigned short*)ws; ws += 512;
  unsigned short* sh16 = (unsigned short*)ws; ws += 512;
  float* gpool = (float*)ws; ws += 131072;

  hipMemsetAsync(degs_i, 0, 200000, stream);
  hipMemsetAsync(fill, 0, 200000, stream);
  // zero X16 pad rows in each slice slab so GEMM pad output is exactly b[c]
  for (int s = 0; s < 8; ++s)
    hipMemsetAsync(X16 + (size_t)s * SLAB + (size_t)N_NODESC * 32, 0,
                   (size_t)(N_PAD - N_NODESC) * 64, stream);

  wprep_k<<<1280, 256, 0, stream>>>(W, Wt);
  ew_k<<<120, 256, 0, stream>>>(edge_emb, W, EWt);
  atom_encode_k<<<12500, 256, 0, stream>>>(nfeat, atom_emb, h16);
  deg_k<<<3125, 256, 0, stream>>>(dst, degs_i);
  scan_partial_k<<<49, 256, 0, stream>>>(degs_i, bsum);
  scan_sums_k<<<1, 64, 0, stream>>>(bsum, boff);
  scan_final_k<<<49, 256, 0, stream>>>(degs_i, boff, row_start);
  scatter_k<<<25000, 256, 0, stream>>>(src, dst, row_start, fill, csrc, ceid);
  cntf_k<<<196, 256, 0, stream>>>(ceid, row_start, efeat, cntf);

  // layer 0 aggregate: atom-encoded h16, no BN
  aggregate_t<0><<<12504, 256, 0, stream>>>(h16, csrc, row_start,
                                            nullptr, nullptr, X16);
  for (int l = 0; l < 5; ++l) {
    gemm_k<<<dim3(MTILES, 2), 256, 0, stream>>>(X16, Wt + l * 65536, cntf,
                                                EWt + l * 8192, b + l * 256,
                                                Y16, Pp);
    stats_finalize_k<<<256, 128, 0, stream>>>(Pp, b + l * 256, gamma + l * 256,
                                              beta + l * 256, scale, shiftv,
                                              sc16, sh16);
    if (l < 4)
      aggregate_t<1><<<12504, 256, 0, stream>>>(Y16, csrc, row_start,
                                                sc16, sh16, X16);
  }

  pool_k<<<128, 512, 0, stream>>>(Y16, gid, scale, shiftv, gpool);
  final_k<<<128, 128, 0, stream>>>(gpool, Wp, bp, out);
}

// Round 21
// 557.904 us; speedup vs baseline: 1.5600x; 1.0042x over previous
//
#include <hip/hip_runtime.h>

#define N_NODESC 50000
#define N_PAD 50176          // 392 * 128
#define N_EDGESC 800000
#define N_GRAPHSC 128
#define EMBEDC 256
#define MTILES 392
#define SLAB ((long)N_PAD * 32)   // halves per 32-col slice slab
#define NRANGE 6272               // N_PAD/8: node range per scatter slice

typedef __attribute__((ext_vector_type(8))) _Float16 hf8;
typedef __attribute__((ext_vector_type(4))) float fx4;

__device__ __forceinline__ float h2f(unsigned short u) {
  _Float16 h = *(_Float16*)&u;
  return (float)h;
}
__device__ __forceinline__ unsigned short f2h(float f) {
  _Float16 h = (_Float16)f;
  return *(unsigned short*)&h;
}
__device__ __forceinline__ unsigned int packh2(float lo, float hi) {
  return (unsigned int)f2h(lo) | ((unsigned int)f2h(hi) << 16);
}

// ------------------------------------------- atom encoder (slice-major h16)
__global__ __launch_bounds__(256) void atom_encode_k(
    const int* __restrict__ nfeat, const float* __restrict__ atom_emb,
    unsigned short* __restrict__ h16)
{
  int w = threadIdx.x >> 6, lane = threadIdx.x & 63;
  int n = blockIdx.x * 4 + w;
  if (n >= N_NODESC) return;
  const int* nf = nfeat + n * 9;
  float ax = 0.f, ay = 0.f, az = 0.f, aw = 0.f;
#pragma unroll
  for (int c = 0; c < 9; ++c) {
    int idx = nf[c];
    const float4* row = (const float4*)(atom_emb + (c * 128 + idx) * EMBEDC);
    float4 v = row[lane];
    ax += v.x; ay += v.y; az += v.z; aw += v.w;
  }
  ushort4 o;
  o.x = f2h(ax); o.y = f2h(ay); o.z = f2h(az); o.w = f2h(aw);
  int col = lane * 4;
  *(ushort4*)(h16 + (long)(col >> 5) * SLAB + (long)n * 32 + (col & 31)) = o;
}

// ---------------------------------------------------------------- degree count
__global__ __launch_bounds__(256) void deg_k(
    const int* __restrict__ dst, int* __restrict__ degs)
{
  int e = blockIdx.x * 256 + threadIdx.x;
  if (e >= N_EDGESC) return;
  atomicAdd(&degs[dst[e]], 1);
}

// ------------------------------------------- parallel 3-phase exclusive scan
__global__ __launch_bounds__(256) void scan_partial_k(
    const int* __restrict__ deg, int* __restrict__ bsum)
{
  __shared__ int buf[256];
  int b = blockIdx.x, t = threadIdx.x;
  int idx0 = b * 1024 + t * 4;
  int s = 0;
#pragma unroll
  for (int i = 0; i < 4; ++i) {
    int idx = idx0 + i;
    if (idx < N_NODESC) s += deg[idx];
  }
  buf[t] = s;
  __syncthreads();
  for (int off = 1; off < 256; off <<= 1) {
    int add = (t >= off) ? buf[t - off] : 0;
    __syncthreads();
    buf[t] += add;
    __syncthreads();
  }
  if (t == 255) bsum[b] = buf[255];
}
__global__ __launch_bounds__(64) void scan_sums_k(
    const int* __restrict__ bsum, int* __restrict__ boff)
{
  __shared__ int buf[64];
  int t = threadIdx.x;
  int v = (t < 49) ? bsum[t] : 0;
  buf[t] = v;
  __syncthreads();
  for (int off = 1; off < 64; off <<= 1) {
    int add = (t >= off) ? buf[t - off] : 0;
    __syncthreads();
    buf[t] += add;
    __syncthreads();
  }
  if (t < 49) boff[t] = buf[t] - v;   // exclusive
  if (t == 48) boff[49] = buf[48];    // total
}
__global__ __launch_bounds__(256) void scan_final_k(
    const int* __restrict__ deg, const int* __restrict__ boff,
    int* __restrict__ row_start)
{
  __shared__ int buf[256];
  int b = blockIdx.x, t = threadIdx.x;
  int idx0 = b * 1024 + t * 4;
  int loc[4];
  int s = 0;
#pragma unroll
  for (int i = 0; i < 4; ++i) {
    int idx = idx0 + i;
    int v = (idx < N_NODESC) ? deg[idx] : 0;
    loc[i] = v; s += v;
  }
  buf[t] = s;
  __syncthreads();
  for (int off = 1; off < 256; off <<= 1) {
    int add = (t >= off) ? buf[t - off] : 0;
    __syncthreads();
    buf[t] += add;
    __syncthreads();
  }
  int run = boff[b] + buf[t] - s;
#pragma unroll
  for (int i = 0; i < 4; ++i) {
    int idx = idx0 + i;
    if (idx < N_NODESC) row_start[idx] = run;
    run += loc[i];
  }
  if (b == 48 && t == 255) row_start[N_NODESC] = boff[49];
}

// ------------------------------------ CSR scatter, range-partitioned by dst
__global__ __launch_bounds__(256) void scatter_k(
    const int* __restrict__ src, const int* __restrict__ dst,
    const int* __restrict__ row_start, int* __restrict__ fill,
    int* __restrict__ csrc, int* __restrict__ ceid)
{
  int b = blockIdx.x;
  int r = b & 7;
  int e = (b >> 3) * 256 + threadIdx.x;
  if (e >= N_EDGESC) return;
  int d = dst[e];
  int lo = r * NRANGE;
  if (d < lo || d >= lo + NRANGE) return;
  int pos = row_start[d] + atomicAdd(&fill[d], 1);
  csrc[pos] = src[e];
  ceid[pos] = e;
}

// ------------------- per-node edge-feature histogram -> fp16 cnt/(deg+1)
__global__ __launch_bounds__(256) void cntf_k(
    const int* __restrict__ ceid, const int* __restrict__ row_start,
    const int* __restrict__ efeat, unsigned short* __restrict__ cntf)
{
  __shared__ int lc[256 * 25];
  int t = threadIdx.x;
  int n = blockIdx.x * 256 + t;          // 196*256 == 50176 == N_PAD
  int base = t * 25;
#pragma unroll
  for (int j = 0; j < 24; ++j) lc[base + j] = 0;
  float inv = 0.f;
  if (n < N_NODESC) {
    int s0 = row_start[n], s1 = row_start[n + 1];
    inv = 1.0f / (float)(s1 - s0 + 1);
    for (int e = s0; e < s1; ++e) {
      int eid = ceid[e];
      int v0 = efeat[eid * 3 + 0];
      int v1 = efeat[eid * 3 + 1];
      int v2 = efeat[eid * 3 + 2];
      lc[base + v0]++;
      lc[base + 8 + v1]++;
      lc[base + 16 + v2]++;
    }
  }
  unsigned int* o = (unsigned int*)(cntf + (long)n * 32);
#pragma unroll
  for (int j = 0; j < 12; ++j)
    o[j] = packh2((float)lc[base + 2 * j] * inv, (float)lc[base + 2 * j + 1] * inv);
#pragma unroll
  for (int j = 12; j < 16; ++j) o[j] = 0u;
}

// ------------------------------------------------ W transpose + fp16 convert
__global__ __launch_bounds__(256) void wprep_k(
    const float* __restrict__ W, unsigned short* __restrict__ Wt)
{
  int tid = blockIdx.x * 256 + threadIdx.x;     // 5*65536
  int l = tid >> 16, r = tid & 65535;
  int n = r >> 8, k = r & 255;
  float w = W[(long)l * 65536 + k * 256 + n];
  Wt[tid] = f2h(w);                             // tid == l*65536 + n*256 + k
}

// ------------------------------ EW[l] = E[l] @ W[l], stored transposed [c'][32]
__global__ __launch_bounds__(256) void ew_k(
    const float* __restrict__ edge_emb, const float* __restrict__ W,
    unsigned short* __restrict__ EWt)
{
  __shared__ float e[256];
  int l = blockIdx.x / 24, j = blockIdx.x % 24;
  int c = threadIdx.x;
  e[c] = edge_emb[(long)l * 6144 + j * 256 + c];
  __syncthreads();
  const float* Wl = W + (long)l * 65536;
  float acc = 0.f;
#pragma unroll 8
  for (int k = 0; k < 256; ++k) acc += e[k] * Wl[k * 256 + c];
  EWt[((long)l * 256 + c) * 32 + j] = f2h(acc);
}

// ---------------------------------------------------------------- aggregation
// XCD-sliced (slice = blockIdx%8 -> slab L2-resident per XCD). Wave = 8 nodes
// x 8 lanes (2 edge-groups x 4 chunks of 16B); 6 gathers in flight per lane.
// Packed fp16 accumulate, single fp32 flush. Histogram folded into GEMM.
template<int FUSE_BN>
__device__ __forceinline__ hf8 bnval(const uint4 u, const hf8 scv, const hf8 shv)
{
  union { uint4 u4; hf8 h8; } cv;
  cv.u4 = u;
  hf8 y = cv.h8;
  if (FUSE_BN) {
    y = y * scv + shv;                        // v_pk_fma_f16 x4
    y = __builtin_elementwise_max(y, (hf8)0); // v_pk_max_f16 x4
  }
  return y;
}

template<int FUSE_BN>
__global__ __launch_bounds__(256) void aggregate_t(
    const unsigned short* __restrict__ tab_base,
    const int* __restrict__ csrc, const int* __restrict__ row_start,
    const unsigned short* __restrict__ sc16,
    const unsigned short* __restrict__ sh16,
    unsigned short* __restrict__ X16)
{
  int bid = blockIdx.x;
  int s = bid & 7;                               // slice == XCD (heuristic)
  int grp = bid >> 3;
  int lane = threadIdx.x & 63;
  int w = threadIdx.x >> 6;
  int nd = lane >> 3;            // node within wave (8)
  int g = (lane >> 2) & 1;       // edge group (2)
  int q = lane & 3;              // 16B chunk (4)
  int n = grp * 32 + w * 8 + nd; // 1563 grps * 32 = 50016 >= 50000
  if (n >= N_NODESC) return;
  const unsigned short* tab = tab_base + (long)s * SLAB;
  hf8 scv = (hf8)0, shv = (hf8)0;
  if (FUSE_BN) {
    scv = *(const hf8*)(sc16 + s * 32 + q * 8);
    shv = *(const hf8*)(sh16 + s * 32 + q * 8);
  }
  int s0 = row_start[n], s1 = row_start[n + 1];
  hf8 hacc = (hf8)0;                             // packed fp16 accumulator
  if (g == 0) {                                  // self row (once, pre-reduce)
    uint4 u = *(const uint4*)(tab + (long)n * 32 + q * 8);
    hacc = hacc + bnval<FUSE_BN>(u, scv, shv);
  }
  int e = s0 + g;
  for (; e + 10 < s1; e += 12) {                 // 6 edges in flight per lane
    int i0 = csrc[e];
    int i1 = csrc[e + 2];
    int i2 = csrc[e + 4];
    int i3 = csrc[e + 6];
    int i4 = csrc[e + 8];
    int i5 = csrc[e + 10];
    uint4 u0 = *(const uint4*)(tab + (long)i0 * 32 + q * 8);
    uint4 u1 = *(const uint4*)(tab + (long)i1 * 32 + q * 8);
    uint4 u2 = *(const uint4*)(tab + (long)i2 * 32 + q * 8);
    uint4 u3 = *(const uint4*)(tab + (long)i3 * 32 + q * 8);
    uint4 u4 = *(const uint4*)(tab + (long)i4 * 32 + q * 8);
    uint4 u5 = *(const uint4*)(tab + (long)i5 * 32 + q * 8);
    hacc = hacc + bnval<FUSE_BN>(u0, scv, shv);
    hacc = hacc + bnval<FUSE_BN>(u1, scv, shv);
    hacc = hacc + bnval<FUSE_BN>(u2, scv, shv);
    hacc = hacc + bnval<FUSE_BN>(u3, scv, shv);
    hacc = hacc + bnval<FUSE_BN>(u4, scv, shv);
    hacc = hacc + bnval<FUSE_BN>(u5, scv, shv);
  }
  if (e + 4 < s1) {                              // 3-deep cleanup
    int i0 = csrc[e];
    int i1 = csrc[e + 2];
    int i2 = csrc[e + 4];
    uint4 u0 = *(const uint4*)(tab + (long)i0 * 32 + q * 8);
    uint4 u1 = *(const uint4*)(tab + (long)i1 * 32 + q * 8);
    uint4 u2 = *(const uint4*)(tab + (long)i2 * 32 + q * 8);
    hacc = hacc + bnval<FUSE_BN>(u0, scv, shv);
    hacc = hacc + bnval<FUSE_BN>(u1, scv, shv);
    hacc = hacc + bnval<FUSE_BN>(u2, scv, shv);
    e += 6;
  }
  for (; e < s1; e += 2) {
    int i0 = csrc[e];
    uint4 u = *(const uint4*)(tab + (long)i0 * 32 + q * 8);
    hacc = hacc + bnval<FUSE_BN>(u, scv, shv);
  }
  // fp32 flush, then reduce over the 2 edge-groups (lane bit 2)
  float a[8];
#pragma unroll
  for (int k = 0; k < 8; ++k) a[k] = (float)hacc[k];
#pragma unroll
  for (int k = 0; k < 8; ++k) a[k] += __shfl_xor(a[k], 4);
  if (g == 0) {                                  // 4 lanes/node write 64B
    float inv = 1.0f / (float)(s1 - s0 + 1);
    uint4 o;
    o.x = packh2(a[0] * inv, a[1] * inv);
    o.y = packh2(a[2] * inv, a[3] * inv);
    o.z = packh2(a[4] * inv, a[5] * inv);
    o.w = packh2(a[6] * inv, a[7] * inv);
    *(uint4*)(X16 + (long)s * SLAB + (long)n * 32 + q * 8) = o;
  }
}

// ---------------------------------------------------------------- MFMA GEMM fp16
// Y16 = fp16([X | cntf] @ [W ; EW] + b), K = 256 + 32(24 used).
__global__ __launch_bounds__(256) void gemm_k(
    const unsigned short* __restrict__ X16, const unsigned short* __restrict__ Bt,
    const unsigned short* __restrict__ cntf, const unsigned short* __restrict__ EWt,
    const float* __restrict__ bl, unsigned short* __restrict__ Y16,
    float* __restrict__ Pp)
{
  __shared__ unsigned short As[128 * 72];
  __shared__ unsigned short Bs[128 * 72];
  __shared__ float red_s[256];
  __shared__ float red_q[256];

  int t = threadIdx.x;
  int bm = blockIdx.x, bn = blockIdx.y;
  int row0 = bm * 128, nc0 = bn * 128;
  int w = t >> 6, l = t & 63;
  int wr = w >> 1, wc = w & 1;
  int lr = l & 15, lk = l >> 4;

  fx4 acc[4][4];
#pragma unroll
  for (int i = 0; i < 4; ++i)
#pragma unroll
    for (int j = 0; j < 4; ++j) acc[i][j] = (fx4){0.f, 0.f, 0.f, 0.f};

  for (int kb = 0; kb < 5; ++kb) {
    __syncthreads();
    if (kb < 4) {
      int kc = kb * 64;
#pragma unroll
      for (int q = 0; q < 2; ++q) {
        int id = q * 256 + t;
        int r = id >> 2, c16 = (id & 3) << 4;
        int ktot = kc + c16;
        long gA = (long)(ktot >> 5) * SLAB + (long)(row0 + r) * 32 + (ktot & 31);
        long gB = (long)(nc0 + r) * 256 + ktot;
        *(uint4*)&As[r * 72 + c16] = *(const uint4*)(X16 + gA);
        *(uint4*)&As[r * 72 + c16 + 8] = *(const uint4*)(X16 + gA + 8);
        *(uint4*)&Bs[r * 72 + c16] = *(const uint4*)(Bt + gB);
        *(uint4*)&Bs[r * 72 + c16 + 8] = *(const uint4*)(Bt + gB + 8);
      }
    } else {
#pragma unroll
      for (int q = 0; q < 2; ++q) {
        int id = q * 256 + t;
        int r = id >> 2, c8 = (id & 3) << 3;
        *(uint4*)&As[r * 72 + c8] = *(const uint4*)(cntf + (long)(row0 + r) * 32 + c8);
        *(uint4*)&Bs[r * 72 + c8] = *(const uint4*)(EWt + (long)(nc0 + r) * 32 + c8);
      }
    }
    __syncthreads();
    int nks = (kb < 4) ? 2 : 1;
    for (int ks = 0; ks < nks; ++ks) {
      int ko = ks * 32 + lk * 8;
      hf8 af[4], bf[4];
#pragma unroll
      for (int f = 0; f < 4; ++f) {
        af[f] = *(const hf8*)&As[(wr * 64 + f * 16 + lr) * 72 + ko];
        bf[f] = *(const hf8*)&Bs[(wc * 64 + f * 16 + lr) * 72 + ko];
      }
#pragma unroll
      for (int fm = 0; fm < 4; ++fm)
#pragma unroll
        for (int fn = 0; fn < 4; ++fn)
          acc[fm][fn] = __builtin_amdgcn_mfma_f32_16x16x32_f16(
              af[fm], bf[fn], acc[fm][fn], 0, 0, 0);
    }
  }

  float bcol[4];
#pragma unroll
  for (int fn = 0; fn < 4; ++fn) bcol[fn] = bl[nc0 + wc * 64 + fn * 16 + lr];
  float sp[4] = {0.f, 0.f, 0.f, 0.f}, qp[4] = {0.f, 0.f, 0.f, 0.f};
#pragma unroll
  for (int fm = 0; fm < 4; ++fm)
#pragma unroll
    for (int fn = 0; fn < 4; ++fn) {
      int cl = wc * 64 + fn * 16 + lr;
      int col = nc0 + cl;
      long ybase = (long)(col >> 5) * SLAB + (col & 31);
#pragma unroll
      for (int j = 0; j < 4; ++j) {
        int rl = wr * 64 + fm * 16 + lk * 4 + j;
        float v = acc[fm][fn][j] + bcol[fn];
        Y16[ybase + (long)(row0 + rl) * 32] = f2h(v);
        sp[fn] += v; qp[fn] += v * v;
      }
    }
#pragma unroll
  for (int fn = 0; fn < 4; ++fn) {
    sp[fn] += __shfl_xor(sp[fn], 16);
    sp[fn] += __shfl_xor(sp[fn], 32);
    qp[fn] += __shfl_xor(qp[fn], 16);
    qp[fn] += __shfl_xor(qp[fn], 32);
  }
  if (lk == 0) {
#pragma unroll
    for (int fn = 0; fn < 4; ++fn) {
      red_s[w * 64 + fn * 16 + lr] = sp[fn];
      red_q[w * 64 + fn * 16 + lr] = qp[fn];
    }
  }
  __syncthreads();
  if (t < 128) {
    float s = red_s[t] + red_s[128 + t];
    float q = red_q[t] + red_q[128 + t];
    float* p = Pp + (bm * 2 + bn) * 256;
    p[t] = s;
    p[128 + t] = q;
  }
}

// --------------------------- BN stats reduce + finalize (256 blocks, parallel)
__global__ __launch_bounds__(128) void stats_finalize_k(
    const float* __restrict__ Pp, const float* __restrict__ bl,
    const float* __restrict__ gamma, const float* __restrict__ beta,
    float* __restrict__ scale, float* __restrict__ shiftv,
    unsigned short* __restrict__ sc16, unsigned short* __restrict__ sh16)
{
  __shared__ float red_s[128];
  __shared__ float red_q[128];
  int c = blockIdx.x;                 // one column per block
  int half = c >> 7, cl = c & 127;
  int t = threadIdx.x;
  float s = 0.f, q = 0.f;
  for (int bm = t; bm < MTILES; bm += 128) {
    const float* p = Pp + (bm * 2 + half) * 256;
    s += p[cl];
    q += p[128 + cl];
  }
  red_s[t] = s; red_q[t] = q;
  __syncthreads();
#pragma unroll
  for (int off = 64; off > 0; off >>= 1) {
    if (t < off) {
      red_s[t] += red_s[t + off];
      red_q[t] += red_q[t + off];
    }
    __syncthreads();
  }
  if (t == 0) {
    s = red_s[0]; q = red_q[0];
    float bc = bl[c];
    s -= (float)(N_PAD - N_NODESC) * bc;
    q -= (float)(N_PAD - N_NODESC) * bc * bc;
    const float invN = 1.0f / (float)N_NODESC;
    float mu = s * invN;
    float var = q * invN - mu * mu;
    float rsq = rsqrtf(var + 1e-5f);
    float sc = gamma[c] * rsq;
    float sh = beta[c] - mu * sc;
    scale[c] = sc;
    shiftv[c] = sh;
    sc16[c] = f2h(sc);
    sh16[c] = f2h(sh);
  }
}

// ---------------------------------------------------------------- mean pooling
__device__ __forceinline__ int lower_bound_g(const int* gid, int n, int g)
{
  int lo = 0, hi = n;
  while (lo < hi) {
    int mid = (lo + hi) >> 1;
    if (gid[mid] < g) lo = mid + 1; else hi = mid;
  }
  return lo;
}

__global__ __launch_bounds__(512) void pool_k(
    const unsigned short* __restrict__ Y16, const int* __restrict__ gid,
    const float* __restrict__ scale, const float* __restrict__ shiftv,
    float* __restrict__ gpool)
{
  __shared__ float red[8 * 256];
  int g = blockIdx.x;
  int lo = lower_bound_g(gid, N_NODESC, g);
  int hi = lower_bound_g(gid, N_NODESC, g + 1);
  int t = threadIdx.x;
  int w = t >> 6, lane = t & 63;
  int col = lane * 4;
  long ybase = (long)(col >> 5) * SLAB + (col & 31);
  float4 sc = *(const float4*)(scale + col);
  float4 sh = *(const float4*)(shiftv + col);
  float a0 = 0.f, a1 = 0.f, a2 = 0.f, a3 = 0.f;
  for (int r = lo + w; r < hi; r += 8) {
    ushort4 u = *(const ushort4*)(Y16 + ybase + (long)r * 32);
    a0 += fmaxf(0.f, h2f(u.x) * sc.x + sh.x);
    a1 += fmaxf(0.f, h2f(u.y) * sc.y + sh.y);
    a2 += fmaxf(0.f, h2f(u.z) * sc.z + sh.z);
    a3 += fmaxf(0.f, h2f(u.w) * sc.w + sh.w);
  }
  *(float4*)&red[w * 256 + col] = make_float4(a0, a1, a2, a3);
  __syncthreads();
  if (t < 256) {
    float s = 0.f;
#pragma unroll
    for (int j = 0; j < 8; ++j) s += red[j * 256 + t];
    int c = hi - lo;
    gpool[g * 256 + t] = s / (float)(c > 0 ? c : 1);
  }
}

// ---------------------------------------------------------------- final proj
__global__ __launch_bounds__(128) void final_k(
    const float* __restrict__ gpool, const float* __restrict__ Wp,
    const float* __restrict__ bp, float* __restrict__ out)
{
  __shared__ float gr[256];
  int g = blockIdx.x, t = threadIdx.x;
  gr[t] = gpool[g * 256 + t];
  gr[t + 128] = gpool[g * 256 + t + 128];
  __syncthreads();
  float acc = bp[t];
#pragma unroll 8
  for (int k = 0; k < 256; ++k) acc += gr[k] * Wp[k * 128 + t];
  out[g * 128 + t] = acc;
}

// ---------------------------------------------------------------- launcher
extern "C" void kernel_launch(void* const* d_in, const int* in_sizes, int n_in,
                              void* d_out, int out_size, void* d_ws, size_t ws_size,
                              hipStream_t stream)
{
  (void)in_sizes; (void)n_in; (void)out_size; (void)ws_size;
  const int* nfeat = (const int*)d_in[0];
  const int* efeat = (const int*)d_in[1];
  const int* src = (const int*)d_in[2];
  const int* dst = (const int*)d_in[3];
  const int* gid = (const int*)d_in[4];
  const float* atom_emb = (const float*)d_in[5];
  const float* edge_emb = (const float*)d_in[6];
  const float* W = (const float*)d_in[7];
  const float* b = (const float*)d_in[8];
  const float* gamma = (const float*)d_in[9];
  const float* beta = (const float*)d_in[10];
  const float* Wp = (const float*)d_in[11];
  const float* bp = (const float*)d_in[12];
  float* out = (float*)d_out;

  char* ws = (char*)d_ws;
  unsigned short* h16 = (unsigned short*)ws; ws += (size_t)N_PAD * 512;
  unsigned short* Y16 = (unsigned short*)ws; ws += (size_t)N_PAD * 512;
  unsigned short* X16 = (unsigned short*)ws; ws += (size_t)N_PAD * 512;
  unsigned short* Wt = (unsigned short*)ws; ws += 5 * 65536 * 2;
  unsigned short* EWt = (unsigned short*)ws; ws += 5 * 256 * 32 * 2;
  unsigned short* cntf = (unsigned short*)ws; ws += (size_t)N_PAD * 32 * 2;
  int* csrc = (int*)ws; ws += 3200000;
  int* ceid = (int*)ws; ws += 3200000;
  int* row_start = (int*)ws; ws += 200064;
  int* degs_i = (int*)ws; ws += 200064;
  int* fill = (int*)ws; ws += 200064;
  int* bsum = (int*)ws; ws += 256;
  int* boff = (int*)ws; ws += 256;
  float* Pp = (float*)ws; ws += MTILES * 2 * 256 * 4;
  float* scale = (float*)ws; ws += 1024;
  float* shiftv = (float*)ws; ws += 1024;
  unsigned short* sc16 = (unsigned short*)ws; ws += 512;
  unsigned short* sh16 = (unsigned short*)ws; ws += 512;
  float* gpool = (float*)ws; ws += 131072;

  hipMemsetAsync(degs_i, 0, 200000, stream);
  hipMemsetAsync(fill, 0, 200000, stream);
  // zero X16 pad rows in each slice slab so GEMM pad output is exactly b[c]
  for (int s = 0; s < 8; ++s)
    hipMemsetAsync(X16 + (size_t)s * SLAB + (size_t)N_NODESC * 32, 0,
                   (size_t)(N_PAD - N_NODESC) * 64, stream);

  wprep_k<<<1280, 256, 0, stream>>>(W, Wt);
  ew_k<<<120, 256, 0, stream>>>(edge_emb, W, EWt);
  atom_encode_k<<<12500, 256, 0, stream>>>(nfeat, atom_emb, h16);
  deg_k<<<3125, 256, 0, stream>>>(dst, degs_i);
  scan_partial_k<<<49, 256, 0, stream>>>(degs_i, bsum);
  scan_sums_k<<<1, 64, 0, stream>>>(bsum, boff);
  scan_final_k<<<49, 256, 0, stream>>>(degs_i, boff, row_start);
  scatter_k<<<25000, 256, 0, stream>>>(src, dst, row_start, fill, csrc, ceid);
  cntf_k<<<196, 256, 0, stream>>>(ceid, row_start, efeat, cntf);

  // layer 0 aggregate: atom-encoded h16, no BN
  aggregate_t<0><<<12504, 256, 0, stream>>>(h16, csrc, row_start,
                                            nullptr, nullptr, X16);
  for (int l = 0; l < 5; ++l) {
    gemm_k<<<dim3(MTILES, 2), 256, 0, stream>>>(X16, Wt + l * 65536, cntf,
                                                EWt + l * 8192, b + l * 256,
                                                Y16, Pp);
    stats_finalize_k<<<256, 128, 0, stream>>>(Pp, b + l * 256, gamma + l * 256,
                                              beta + l * 256, scale, shiftv,
                                              sc16, sh16);
    if (l < 4)
      aggregate_t<1><<<12504, 256, 0, stream>>>(Y16, csrc, row_start,
                                                sc16, sh16, X16);
  }

  pool_k<<<128, 512, 0, stream>>>(Y16, gid, scale, shiftv, gpool);
  final_k<<<128, 128, 0, stream>>>(gpool, Wp, bp, out);
}